// Round 18
// baseline (276.794 us; speedup 1.0000x reference)
//
#include <hip/hip_runtime.h>
#include <hip/hip_bf16.h>

// ---- problem constants ----
#define B_     16
#define NBAND  4
#define HP     56
#define WP     56
#define C_     96
#define NHEADS 3
#define HD     32
#define NT     196                 // tokens per window
#define NTP    224                 // padded to 14x16
#define BW     1024                // windows
#define HID    384
#define NTOK   200704

typedef unsigned short u16;
typedef short s16;
typedef __attribute__((ext_vector_type(8))) s16   short8_t;  // 8 bf16 (4 VGPR)
typedef __attribute__((ext_vector_type(4))) s16   short4_t;
typedef __attribute__((ext_vector_type(4))) float f32x4;

__device__ __forceinline__ float bf2f(u16 u) {
    union { float f; unsigned int i; } x; x.i = ((unsigned int)u) << 16; return x.f;
}
// HW RNE conversion
__device__ __forceinline__ u16 f2bf(float f) {
    __hip_bfloat16 h = __float2bfloat16(f);
    union { __hip_bfloat16 h; u16 u; } c; c.h = h; return c.u;
}
// sigmoid-GELU: x * sigmoid(1.702x) (validated round 10)
__device__ __forceinline__ float gelu_f(float a) {
    return __fdividef(a, 1.0f + __expf(-1.702f * a));
}

// ---- workspace layout (bf16 elements) ----
#define WT_OFF   0          // qkv_w^T  [288][96]
#define PJT_OFF  27648      // proj_w^T [96][96]
#define F1T_OFF  36864      // fc1_w^T  [384][96]
#define F2T_OFF  73728      // fc2_w^T  [96][384]
#define WS_ELEMS 110592     // * 2 bytes = 221,184 B

__global__ __launch_bounds__(256) void setup_kernel(
    const float* __restrict__ qkv_w, const float* __restrict__ proj_w,
    const float* __restrict__ fc1_w, const float* __restrict__ fc2_w,
    u16* __restrict__ ws)
{
    int i0 = blockIdx.x * 256 + threadIdx.x;
    int stride = gridDim.x * 256;
    for (int e = i0; e < 27648; e += stride) {          // wT[n][k] = qkv_w[k][n]
        int n = e / 96, k = e - n * 96;
        ws[WT_OFF + e] = f2bf(qkv_w[k * 288 + n]);
    }
    for (int e = i0; e < 9216; e += stride) {           // pjT[n][k]
        int n = e / 96, k = e - n * 96;
        ws[PJT_OFF + e] = f2bf(proj_w[k * 96 + n]);
    }
    for (int e = i0; e < 36864; e += stride) {          // f1T[n][k], n<384
        int n = e / 96, k = e - n * 96;
        ws[F1T_OFF + e] = f2bf(fc1_w[k * 384 + n]);
    }
    for (int e = i0; e < 36864; e += stride) {          // f2T[n][k], n<96, k<384
        int n = e / 384, k = e - n * 384;
        ws[F2T_OFF + e] = f2bf(fc2_w[k * 96 + n]);
    }
}

// =====================================================================
// FUSED kernel v7 = r17 + (a) log2e folded into Q scale so softmax uses
// exp2f directly (drops 1 v_mul per exp on the serial PV path), and
// (b) pairwise max tree (depth 12 -> 4). Everything else r17-identical.
// =====================================================================
#define NWV    7
#define QK_LD  40    // Q/K row stride (u16)
#define VT_LD  232   // V^T row stride
#define STG_LD 40    // per-wave staging row stride
#define X2_LD  104   // x2' row stride (u16)
#define ABUF_ELEMS (2 * NTP * QK_LD + HD * VT_LD)   // 25,344 u16 = 50,688 B

__global__ __launch_bounds__(448) void fused_kernel(
    const float* __restrict__ x,
    const u16*  __restrict__ ws,
    const float* __restrict__ qkv_b,
    const float* __restrict__ proj_b,
    const float* __restrict__ g1, const float* __restrict__ b1,
    const float* __restrict__ g2, const float* __restrict__ b2,
    const float* __restrict__ fc1_b, const float* __restrict__ fc2_b,
    float* __restrict__ out)
{
    __shared__ __align__(16) u16 ABuf[ABUF_ELEMS];           // Qs|Ks|VTs, later X2 (bf16)
    __shared__ __align__(16) u16 Stg[NWV * 2 * 16 * STG_LD]; // 17,920 B
    __shared__ int rowsL[NT];                                //    784 B

    u16* const Qs  = ABuf;
    u16* const Ks  = ABuf + NTP * QK_LD;
    u16* const VTs = ABuf + 2 * NTP * QK_LD;
    u16* const X2  = ABuf;       // alias after head loop; 224*104*2 = 46,592 B

    const int wi  = blockIdx.x;
    const int b   = wi >> 6, ih = (wi >> 3) & 7, iw = wi & 7;
    const int tid = threadIdx.x;
    const int w   = tid >> 6, lane = tid & 63;
    const int l15 = lane & 15, g = lane >> 4;

    // token t=(n,r,col) -> flat row; roll(-3) gather == roll(+3) scatter
    if (tid < NT) {
        int t = tid;
        int n = t / 49, rc = t - n * 49, r = rc / 7, cl = rc - r * 7;
        int hh = ih * 7 + r  + 3; if (hh >= HP) hh -= HP;
        int ww = iw * 7 + cl + 3; if (ww >= WP) ww -= WP;
        rowsL[t] = ((b * NBAND + n) * HP + hh) * WP + ww;
    }
    __syncthreads();

    const u16* wT  = ws + WT_OFF;
    const u16* pjT = ws + PJT_OFF;
    const u16* f1T = ws + F1T_OFF;
    const u16* f2T = ws + F2T_OFF;

    // ---- preload x A-fragments for both owned M-tiles (head-invariant) ----
    short8_t ax[2][3];
    #pragma unroll
    for (int im = 0; im < 2; ++im) {
        int mt = w + NWV * im;
        int t  = mt * 16 + l15;
        bool valid = (t < NT);
        const float* xb = x + (valid ? (size_t)rowsL[t] * C_ : 0);
        #pragma unroll
        for (int ks = 0; ks < 3; ++ks) {
            short8_t a;
            if (valid) {
                const float* p = xb + ks * 32 + g * 8;
                #pragma unroll
                for (int j = 0; j < 8; ++j) a[j] = (s16)f2bf(p[j]);
            } else {
                #pragma unroll
                for (int j = 0; j < 8; ++j) a[j] = 0;
            }
            ax[im][ks] = a;
        }
    }

    f32x4 po[2][6];                       // proj accumulators
    #pragma unroll
    for (int im = 0; im < 2; ++im)
        #pragma unroll
        for (int nj = 0; nj < 6; ++nj)
            po[im][nj] = (f32x4){0.f, 0.f, 0.f, 0.f};

    u16* const st0 = Stg + w * (2 * 16 * STG_LD);

    for (int h = 0; h < NHEADS; ++h) {
        // ---- QKV GEMM for head h: nj outer, B-frags/bias shared (r16) ----
        #pragma unroll
        for (int nj = 0; nj < 6; ++nj) {
            int mat = nj >> 1, nh = nj & 1;
            int ncol = mat * 96 + h * 32 + nh * 16 + l15;
            short8_t bw[3];
            #pragma unroll
            for (int ks = 0; ks < 3; ++ks)
                bw[ks] = *(const short8_t*)(wT + ncol * 96 + ks * 32 + g * 8);
            float bias = qkv_b[ncol];
            int d = nh * 16 + l15;
            #pragma unroll
            for (int im = 0; im < 2; ++im) {
                int mt = w + NWV * im;
                f32x4 acc = {0.f, 0.f, 0.f, 0.f};
                #pragma unroll
                for (int ks = 0; ks < 3; ++ks)
                    acc = __builtin_amdgcn_mfma_f32_16x16x32_bf16(ax[im][ks], bw[ks], acc, 0, 0, 0);
                int trow = mt * 16 + 4 * g;
                if (mat == 0) {
                    // hd^-0.5 * log2(e) folded into Q -> softmax via exp2
                    const float sc = 0.25503492f;
                    #pragma unroll
                    for (int r = 0; r < 4; ++r)
                        Qs[(trow + r) * QK_LD + d] = f2bf((acc[r] + bias) * sc);
                } else if (mat == 1) {
                    #pragma unroll
                    for (int r = 0; r < 4; ++r)
                        Ks[(trow + r) * QK_LD + d] = f2bf(acc[r] + bias);
                } else {                       // V stored transposed
                    short4_t v4;
                    #pragma unroll
                    for (int r = 0; r < 4; ++r) v4[r] = (s16)f2bf(acc[r] + bias);
                    *(short4_t*)(VTs + d * VT_LD + trow) = v4;
                }
            }
        }
        __syncthreads();

        // ---- attention + per-head proj accumulate ----
        #pragma unroll
        for (int im = 0; im < 2; ++im) {
            int mt = w + NWV * im;
            short8_t aQ = *(const short8_t*)(Qs + (mt * 16 + l15) * QK_LD + g * 8);
            f32x4 s[13];
            #pragma unroll
            for (int kt = 0; kt < 13; ++kt) {
                short8_t bK = *(const short8_t*)(Ks + (kt * 16 + l15) * QK_LD + g * 8);
                f32x4 z = {0.f, 0.f, 0.f, 0.f};
                s[kt] = __builtin_amdgcn_mfma_f32_16x16x32_bf16(aQ, bK, z, 0, 0, 0);
            }
            if (l15 >= 4) {                   // keys 192+l15 >= 196 invalid
                #pragma unroll
                for (int r = 0; r < 4; ++r) s[12][r] = -1e30f;
            }
            float m[4], sum[4];
            #pragma unroll
            for (int r = 0; r < 4; ++r) {
                // pairwise max tree (depth 4)
                float a0 = fmaxf(s[0][r],  s[1][r]);
                float a1 = fmaxf(s[2][r],  s[3][r]);
                float a2 = fmaxf(s[4][r],  s[5][r]);
                float a3 = fmaxf(s[6][r],  s[7][r]);
                float a4 = fmaxf(s[8][r],  s[9][r]);
                float a5 = fmaxf(s[10][r], s[11][r]);
                float b0 = fmaxf(a0, a1);
                float b1 = fmaxf(a2, a3);
                float b2 = fmaxf(a4, a5);
                float c0 = fmaxf(b0, b1);
                float c1 = fmaxf(b2, s[12][r]);
                float mm = fmaxf(c0, c1);
                #pragma unroll
                for (int o = 1; o < 16; o <<= 1) mm = fmaxf(mm, __shfl_xor(mm, o, 64));
                m[r] = mm;
                sum[r] = 0.f;
            }

            // exp2+write one P chunk (kp); sum order 0..6 (logits pre-scaled)
            auto stage_chunk = [&](int kp, u16* st) {
                #pragma unroll
                for (int r = 0; r < 4; ++r) {
                    float p0 = exp2f(s[2 * kp][r] - m[r]);
                    sum[r] += p0;
                    st[(4 * g + r) * STG_LD + l15] = f2bf(p0);
                    if (kp < 6) {
                        float p1 = exp2f(s[2 * kp + 1][r] - m[r]);
                        sum[r] += p1;
                        st[(4 * g + r) * STG_LD + 16 + l15] = f2bf(p1);
                    } else {
                        st[(4 * g + r) * STG_LD + 16 + l15] = 0;   // padded keys
                    }
                }
            };

            // PV pipelined (r17): read prev chunk first, then stage next.
            f32x4 o0 = {0.f,0.f,0.f,0.f}, o1 = {0.f,0.f,0.f,0.f};
            stage_chunk(0, st0);                       // prologue: chunk 0 -> buf0
            #pragma unroll
            for (int kp = 0; kp < 7; ++kp) {
                u16* stc = st0 + (kp & 1) * (16 * STG_LD);
                short8_t aP  = *(const short8_t*)(stc + l15 * STG_LD + g * 8);
                short8_t bV0 = *(const short8_t*)(VTs + l15 * VT_LD + kp * 32 + g * 8);
                short8_t bV1 = *(const short8_t*)(VTs + (16 + l15) * VT_LD + kp * 32 + g * 8);
                if (kp < 6)
                    stage_chunk(kp + 1, st0 + ((kp + 1) & 1) * (16 * STG_LD));
                o0 = __builtin_amdgcn_mfma_f32_16x16x32_bf16(aP, bV0, o0, 0, 0, 0);
                o1 = __builtin_amdgcn_mfma_f32_16x16x32_bf16(aP, bV1, o1, 0, 0, 0);
            }
            #pragma unroll
            for (int r = 0; r < 4; ++r) {
                #pragma unroll
                for (int o = 1; o < 16; o <<= 1) sum[r] += __shfl_xor(sum[r], o, 64);
            }

            {
                u16* st = st0;
                #pragma unroll
                for (int r = 0; r < 4; ++r) {
                    float inv = 1.f / sum[r];
                    st[(4 * g + r) * STG_LD + l15]      = f2bf(o0[r] * inv);
                    st[(4 * g + r) * STG_LD + 16 + l15] = f2bf(o1[r] * inv);
                }
                short8_t aO = *(const short8_t*)(st + l15 * STG_LD + g * 8);
                #pragma unroll
                for (int nj = 0; nj < 6; ++nj) {
                    short8_t bw = *(const short8_t*)(pjT + (nj * 16 + l15) * 96 + h * 32 + g * 8);
                    po[im][nj] = __builtin_amdgcn_mfma_f32_16x16x32_bf16(aO, bw, po[im][nj], 0, 0, 0);
                }
            }
        }
        __syncthreads();     // last iteration: fences ABuf for the X2 alias
    }

    // =================================================================
    // Post-attn: register LN + bf16 X2 store (wave-private) + dual-tile
    // MLP. ZERO barriers. (r15/r16/r17-proven)
    // =================================================================
    float pb[6], g1v[6], b1v[6], g2v[6], b2v[6], fbv[6];
    #pragma unroll
    for (int nj = 0; nj < 6; ++nj) {
        int c = nj * 16 + l15;
        pb[nj]  = proj_b[c];
        g1v[nj] = g1[c];  b1v[nj] = b1[c];
        g2v[nj] = g2[c];  b2v[nj] = b2[c];
        fbv[nj] = fc2_b[c];
    }

    short8_t aYv[2][3];
    #pragma unroll
    for (int im = 0; im < 2; ++im) {
        int mt = w + NWV * im;
        int trow = mt * 16 + 4 * g;

        // ---- x2 = attn_out + proj_b (fp32 registers) ----
        f32x4 x2v[6];
        #pragma unroll
        for (int nj = 0; nj < 6; ++nj)
            #pragma unroll
            for (int r = 0; r < 4; ++r)
                x2v[nj][r] = po[im][nj][r] + pb[nj];

        // ---- LN1 stats per row 4g+r (nj-sum + 16-lane shfl) ----
        f32x4 s1 = {0.f,0.f,0.f,0.f}, s2 = {0.f,0.f,0.f,0.f};
        #pragma unroll
        for (int nj = 0; nj < 6; ++nj)
            #pragma unroll
            for (int r = 0; r < 4; ++r) {
                float v = x2v[nj][r];
                s1[r] += v; s2[r] += v * v;
            }
        #pragma unroll
        for (int r = 0; r < 4; ++r) {
            #pragma unroll
            for (int o = 1; o < 16; o <<= 1) {
                s1[r] += __shfl_xor(s1[r], o, 64);
                s2[r] += __shfl_xor(s2[r], o, 64);
            }
        }
        float mu[4], rs[4];
        #pragma unroll
        for (int r = 0; r < 4; ++r) {
            mu[r] = s1[r] * (1.f / 96.f);
            rs[r] = rsqrtf(s2[r] * (1.f / 96.f) - mu[r] * mu[r] + 1e-5f);
        }

        // ---- x2' = x2 + LN1(x2); LN2 stats alongside; bf16 store to X2 ----
        f32x4 t1 = {0.f,0.f,0.f,0.f}, t2 = {0.f,0.f,0.f,0.f};
        #pragma unroll
        for (int nj = 0; nj < 6; ++nj)
            #pragma unroll
            for (int r = 0; r < 4; ++r) {
                float v  = x2v[nj][r];
                float xp = v + (v - mu[r]) * rs[r] * g1v[nj] + b1v[nj];
                x2v[nj][r] = xp;
                t1[r] += xp; t2[r] += xp * xp;
                X2[(trow + r) * X2_LD + nj * 16 + l15] = f2bf(xp);   // wave-private row
            }
        #pragma unroll
        for (int r = 0; r < 4; ++r) {
            #pragma unroll
            for (int o = 1; o < 16; o <<= 1) {
                t1[r] += __shfl_xor(t1[r], o, 64);
                t2[r] += __shfl_xor(t2[r], o, 64);
            }
        }
        float mu2[4], rs2[4];
        #pragma unroll
        for (int r = 0; r < 4; ++r) {
            mu2[r] = t1[r] * (1.f / 96.f);
            rs2[r] = rsqrtf(t2[r] * (1.f / 96.f) - mu2[r] * mu2[r] + 1e-5f);
        }

        // ---- aY: LN2 affine at C-layout write, Stg transpose ----
        #pragma unroll
        for (int ks = 0; ks < 3; ++ks) {
            int njA = 2 * ks, njB = 2 * ks + 1;
            #pragma unroll
            for (int r = 0; r < 4; ++r) {
                st0[(4 * g + r) * STG_LD + l15] =
                    f2bf((x2v[njA][r] - mu2[r]) * rs2[r] * g2v[njA] + b2v[njA]);
                st0[(4 * g + r) * STG_LD + 16 + l15] =
                    f2bf((x2v[njB][r] - mu2[r]) * rs2[r] * g2v[njB] + b2v[njB]);
            }
            aYv[im][ks] = *(const short8_t*)(st0 + l15 * STG_LD + g * 8);   // in-order DS
        }
    }

    // ---- MLP hot loop: both M-tiles per k-step, shared weights ----
    f32x4 p2[2][6];
    #pragma unroll
    for (int im = 0; im < 2; ++im)
        #pragma unroll
        for (int nj = 0; nj < 6; ++nj) p2[im][nj] = (f32x4){0.f, 0.f, 0.f, 0.f};

    short8_t c1[2][3], n1[2][3];
    #pragma unroll
    for (int half = 0; half < 2; ++half)
        #pragma unroll
        for (int k2 = 0; k2 < 3; ++k2)
            c1[half][k2] = *(const short8_t*)(f1T + (half * 16 + l15) * 96 + k2 * 32 + g * 8);

    u16* const stA = st0;
    u16* const stB = st0 + 16 * STG_LD;

    for (int ks = 0; ks < 12; ++ks) {
        // fc2 weights for this ks (shared by both tiles)
        short8_t c2[6];
        #pragma unroll
        for (int nj = 0; nj < 6; ++nj)
            c2[nj] = *(const short8_t*)(f2T + (nj * 16 + l15) * 384 + ks * 32 + g * 8);

        // fc1 + gelu for both tiles into their stage buffers
        #pragma unroll
        for (int im = 0; im < 2; ++im) {
            u16* st = (im == 0) ? stA : stB;
            #pragma unroll
            for (int half = 0; half < 2; ++half) {
                int ncol = (ks * 2 + half) * 16 + l15;
                f32x4 acc = {0.f, 0.f, 0.f, 0.f};
                #pragma unroll
                for (int k2 = 0; k2 < 3; ++k2)
                    acc = __builtin_amdgcn_mfma_f32_16x16x32_bf16(aYv[im][k2], c1[half][k2], acc, 0, 0, 0);
                float bias = fc1_b[ncol];
                #pragma unroll
                for (int r = 0; r < 4; ++r)
                    st[(4 * g + r) * STG_LD + half * 16 + l15] = f2bf(gelu_f(acc[r] + bias));
            }
        }

        // prefetch next-iteration fc1 weights (latency hides under fc2)
        if (ks < 11) {
            #pragma unroll
            for (int half = 0; half < 2; ++half)
                #pragma unroll
                for (int k2 = 0; k2 < 3; ++k2)
                    n1[half][k2] = *(const short8_t*)(f1T + (((ks + 1) * 2 + half) * 16 + l15) * 96 + k2 * 32 + g * 8);
        }

        short8_t aH0 = *(const short8_t*)(stA + l15 * STG_LD + g * 8);
        short8_t aH1 = *(const short8_t*)(stB + l15 * STG_LD + g * 8);
        #pragma unroll
        for (int nj = 0; nj < 6; ++nj) {
            p2[0][nj] = __builtin_amdgcn_mfma_f32_16x16x32_bf16(aH0, c2[nj], p2[0][nj], 0, 0, 0);
            p2[1][nj] = __builtin_amdgcn_mfma_f32_16x16x32_bf16(aH1, c2[nj], p2[1][nj], 0, 0, 0);
        }

        #pragma unroll
        for (int half = 0; half < 2; ++half)
            #pragma unroll
            for (int k2 = 0; k2 < 3; ++k2)
                c1[half][k2] = n1[half][k2];
    }

    // ---- final: out = x2' + fc2_out + fc2_b, scatter via rowsL ----
    #pragma unroll
    for (int im = 0; im < 2; ++im) {
        int mt = w + NWV * im;
        int trow = mt * 16 + 4 * g;
        #pragma unroll
        for (int r = 0; r < 4; ++r) {
            int t = trow + r;
            if (t < NT) {
                float* orow = out + (size_t)rowsL[t] * C_;
                #pragma unroll
                for (int nj = 0; nj < 6; ++nj) {
                    int ncol = nj * 16 + l15;
                    orow[ncol] = bf2f(X2[t * X2_LD + ncol]) + p2[im][nj][r] + fbv[nj];
                }
            }
        }
    }
}

// =====================================================================
extern "C" void kernel_launch(void* const* d_in, const int* in_sizes, int n_in,
                              void* d_out, int out_size, void* d_ws, size_t ws_size,
                              hipStream_t stream)
{
    (void)in_sizes; (void)n_in; (void)out_size; (void)ws_size;

    const float* x      = (const float*)d_in[0];
    const float* qkv_w  = (const float*)d_in[1];
    const float* qkv_b  = (const float*)d_in[2];
    const float* proj_w = (const float*)d_in[3];
    const float* proj_b = (const float*)d_in[4];
    const float* g1     = (const float*)d_in[5];
    const float* b1     = (const float*)d_in[6];
    const float* g2     = (const float*)d_in[7];
    const float* b2     = (const float*)d_in[8];
    const float* fc1_w  = (const float*)d_in[9];
    const float* fc1_b  = (const float*)d_in[10];
    const float* fc2_w  = (const float*)d_in[11];
    const float* fc2_b  = (const float*)d_in[12];
    float* out = (float*)d_out;
    u16* ws = (u16*)d_ws;

    setup_kernel<<<128, 256, 0, stream>>>(qkv_w, proj_w, fc1_w, fc2_w, ws);
    fused_kernel<<<BW, 448, 0, stream>>>(x, ws, qkv_b, proj_b,
                                         g1, b1, g2, b2, fc1_b, fc2_b, out);
}

// Round 19
// 259.339 us; speedup vs baseline: 1.0673x; 1.0673x over previous
//
#include <hip/hip_runtime.h>
#include <hip/hip_bf16.h>

// ---- problem constants ----
#define B_     16
#define NBAND  4
#define HP     56
#define WP     56
#define C_     96
#define NHEADS 3
#define HD     32
#define NT     196                 // tokens per window
#define NTP    224                 // padded to 14x16
#define BW     1024                // windows
#define HID    384
#define NTOK   200704

typedef unsigned short u16;
typedef short s16;
typedef __attribute__((ext_vector_type(8))) s16   short8_t;  // 8 bf16 (4 VGPR)
typedef __attribute__((ext_vector_type(4))) s16   short4_t;
typedef __attribute__((ext_vector_type(4))) float f32x4;

__device__ __forceinline__ float bf2f(u16 u) {
    union { float f; unsigned int i; } x; x.i = ((unsigned int)u) << 16; return x.f;
}
// HW RNE conversion
__device__ __forceinline__ u16 f2bf(float f) {
    __hip_bfloat16 h = __float2bfloat16(f);
    union { __hip_bfloat16 h; u16 u; } c; c.h = h; return c.u;
}
// sigmoid-GELU: x * sigmoid(1.702x) (validated round 10)
__device__ __forceinline__ float gelu_f(float a) {
    return __fdividef(a, 1.0f + __expf(-1.702f * a));
}

// ---- workspace layout (bf16 elements) ----
#define WT_OFF   0          // qkv_w^T  [288][96]
#define PJT_OFF  27648      // proj_w^T [96][96]
#define F1T_OFF  36864      // fc1_w^T  [384][96]
#define F2T_OFF  73728      // fc2_w^T  [96][384]
#define WS_ELEMS 110592     // * 2 bytes = 221,184 B

__global__ __launch_bounds__(256) void setup_kernel(
    const float* __restrict__ qkv_w, const float* __restrict__ proj_w,
    const float* __restrict__ fc1_w, const float* __restrict__ fc2_w,
    u16* __restrict__ ws)
{
    int i0 = blockIdx.x * 256 + threadIdx.x;
    int stride = gridDim.x * 256;
    for (int e = i0; e < 27648; e += stride) {          // wT[n][k] = qkv_w[k][n]
        int n = e / 96, k = e - n * 96;
        ws[WT_OFF + e] = f2bf(qkv_w[k * 288 + n]);
    }
    for (int e = i0; e < 9216; e += stride) {           // pjT[n][k]
        int n = e / 96, k = e - n * 96;
        ws[PJT_OFF + e] = f2bf(proj_w[k * 96 + n]);
    }
    for (int e = i0; e < 36864; e += stride) {          // f1T[n][k], n<384
        int n = e / 96, k = e - n * 96;
        ws[F1T_OFF + e] = f2bf(fc1_w[k * 384 + n]);
    }
    for (int e = i0; e < 36864; e += stride) {          // f2T[n][k], n<96, k<384
        int n = e / 384, k = e - n * 384;
        ws[F2T_OFF + e] = f2bf(fc2_w[k * 96 + n]);
    }
}

// =====================================================================
// FUSED kernel v8 = r17 + log2e folded into Q scale with the RAW
// v_exp_f32 builtin (__builtin_amdgcn_exp2f) — one instruction per exp,
// strictly fewer serial ops than r17's __expf (mul+exp). r18's exp2f
// regression was the PRECISE OCML path; this is the native one.
// Max-tree kept (depth 12 -> 4). Everything else r17-identical.
// =====================================================================
#define NWV    7
#define QK_LD  40    // Q/K row stride (u16)
#define VT_LD  232   // V^T row stride
#define STG_LD 40    // per-wave staging row stride
#define X2_LD  104   // x2' row stride (u16)
#define ABUF_ELEMS (2 * NTP * QK_LD + HD * VT_LD)   // 25,344 u16 = 50,688 B

__global__ __launch_bounds__(448) void fused_kernel(
    const float* __restrict__ x,
    const u16*  __restrict__ ws,
    const float* __restrict__ qkv_b,
    const float* __restrict__ proj_b,
    const float* __restrict__ g1, const float* __restrict__ b1,
    const float* __restrict__ g2, const float* __restrict__ b2,
    const float* __restrict__ fc1_b, const float* __restrict__ fc2_b,
    float* __restrict__ out)
{
    __shared__ __align__(16) u16 ABuf[ABUF_ELEMS];           // Qs|Ks|VTs, later X2 (bf16)
    __shared__ __align__(16) u16 Stg[NWV * 2 * 16 * STG_LD]; // 17,920 B
    __shared__ int rowsL[NT];                                //    784 B

    u16* const Qs  = ABuf;
    u16* const Ks  = ABuf + NTP * QK_LD;
    u16* const VTs = ABuf + 2 * NTP * QK_LD;
    u16* const X2  = ABuf;       // alias after head loop; 224*104*2 = 46,592 B

    const int wi  = blockIdx.x;
    const int b   = wi >> 6, ih = (wi >> 3) & 7, iw = wi & 7;
    const int tid = threadIdx.x;
    const int w   = tid >> 6, lane = tid & 63;
    const int l15 = lane & 15, g = lane >> 4;

    // token t=(n,r,col) -> flat row; roll(-3) gather == roll(+3) scatter
    if (tid < NT) {
        int t = tid;
        int n = t / 49, rc = t - n * 49, r = rc / 7, cl = rc - r * 7;
        int hh = ih * 7 + r  + 3; if (hh >= HP) hh -= HP;
        int ww = iw * 7 + cl + 3; if (ww >= WP) ww -= WP;
        rowsL[t] = ((b * NBAND + n) * HP + hh) * WP + ww;
    }
    __syncthreads();

    const u16* wT  = ws + WT_OFF;
    const u16* pjT = ws + PJT_OFF;
    const u16* f1T = ws + F1T_OFF;
    const u16* f2T = ws + F2T_OFF;

    // ---- preload x A-fragments for both owned M-tiles (head-invariant) ----
    short8_t ax[2][3];
    #pragma unroll
    for (int im = 0; im < 2; ++im) {
        int mt = w + NWV * im;
        int t  = mt * 16 + l15;
        bool valid = (t < NT);
        const float* xb = x + (valid ? (size_t)rowsL[t] * C_ : 0);
        #pragma unroll
        for (int ks = 0; ks < 3; ++ks) {
            short8_t a;
            if (valid) {
                const float* p = xb + ks * 32 + g * 8;
                #pragma unroll
                for (int j = 0; j < 8; ++j) a[j] = (s16)f2bf(p[j]);
            } else {
                #pragma unroll
                for (int j = 0; j < 8; ++j) a[j] = 0;
            }
            ax[im][ks] = a;
        }
    }

    f32x4 po[2][6];                       // proj accumulators
    #pragma unroll
    for (int im = 0; im < 2; ++im)
        #pragma unroll
        for (int nj = 0; nj < 6; ++nj)
            po[im][nj] = (f32x4){0.f, 0.f, 0.f, 0.f};

    u16* const st0 = Stg + w * (2 * 16 * STG_LD);

    for (int h = 0; h < NHEADS; ++h) {
        // ---- QKV GEMM for head h: nj outer, B-frags/bias shared (r16) ----
        #pragma unroll
        for (int nj = 0; nj < 6; ++nj) {
            int mat = nj >> 1, nh = nj & 1;
            int ncol = mat * 96 + h * 32 + nh * 16 + l15;
            short8_t bw[3];
            #pragma unroll
            for (int ks = 0; ks < 3; ++ks)
                bw[ks] = *(const short8_t*)(wT + ncol * 96 + ks * 32 + g * 8);
            float bias = qkv_b[ncol];
            int d = nh * 16 + l15;
            #pragma unroll
            for (int im = 0; im < 2; ++im) {
                int mt = w + NWV * im;
                f32x4 acc = {0.f, 0.f, 0.f, 0.f};
                #pragma unroll
                for (int ks = 0; ks < 3; ++ks)
                    acc = __builtin_amdgcn_mfma_f32_16x16x32_bf16(ax[im][ks], bw[ks], acc, 0, 0, 0);
                int trow = mt * 16 + 4 * g;
                if (mat == 0) {
                    // hd^-0.5 * log2(e) folded into Q -> softmax via raw v_exp
                    const float sc = 0.25503492f;
                    #pragma unroll
                    for (int r = 0; r < 4; ++r)
                        Qs[(trow + r) * QK_LD + d] = f2bf((acc[r] + bias) * sc);
                } else if (mat == 1) {
                    #pragma unroll
                    for (int r = 0; r < 4; ++r)
                        Ks[(trow + r) * QK_LD + d] = f2bf(acc[r] + bias);
                } else {                       // V stored transposed
                    short4_t v4;
                    #pragma unroll
                    for (int r = 0; r < 4; ++r) v4[r] = (s16)f2bf(acc[r] + bias);
                    *(short4_t*)(VTs + d * VT_LD + trow) = v4;
                }
            }
        }
        __syncthreads();

        // ---- attention + per-head proj accumulate ----
        #pragma unroll
        for (int im = 0; im < 2; ++im) {
            int mt = w + NWV * im;
            short8_t aQ = *(const short8_t*)(Qs + (mt * 16 + l15) * QK_LD + g * 8);
            f32x4 s[13];
            #pragma unroll
            for (int kt = 0; kt < 13; ++kt) {
                short8_t bK = *(const short8_t*)(Ks + (kt * 16 + l15) * QK_LD + g * 8);
                f32x4 z = {0.f, 0.f, 0.f, 0.f};
                s[kt] = __builtin_amdgcn_mfma_f32_16x16x32_bf16(aQ, bK, z, 0, 0, 0);
            }
            if (l15 >= 4) {                   // keys 192+l15 >= 196 invalid
                #pragma unroll
                for (int r = 0; r < 4; ++r) s[12][r] = -1e30f;
            }
            float m[4], sum[4];
            #pragma unroll
            for (int r = 0; r < 4; ++r) {
                // pairwise max tree (depth 4)
                float a0 = fmaxf(s[0][r],  s[1][r]);
                float a1 = fmaxf(s[2][r],  s[3][r]);
                float a2 = fmaxf(s[4][r],  s[5][r]);
                float a3 = fmaxf(s[6][r],  s[7][r]);
                float a4 = fmaxf(s[8][r],  s[9][r]);
                float a5 = fmaxf(s[10][r], s[11][r]);
                float b0 = fmaxf(a0, a1);
                float b1 = fmaxf(a2, a3);
                float b2 = fmaxf(a4, a5);
                float c0 = fmaxf(b0, b1);
                float c1 = fmaxf(b2, s[12][r]);
                float mm = fmaxf(c0, c1);
                #pragma unroll
                for (int o = 1; o < 16; o <<= 1) mm = fmaxf(mm, __shfl_xor(mm, o, 64));
                m[r] = mm;
                sum[r] = 0.f;
            }

            // raw v_exp_f32 per element; sum order 0..6 (logits pre-scaled)
            auto stage_chunk = [&](int kp, u16* st) {
                #pragma unroll
                for (int r = 0; r < 4; ++r) {
                    float p0 = __builtin_amdgcn_exp2f(s[2 * kp][r] - m[r]);
                    sum[r] += p0;
                    st[(4 * g + r) * STG_LD + l15] = f2bf(p0);
                    if (kp < 6) {
                        float p1 = __builtin_amdgcn_exp2f(s[2 * kp + 1][r] - m[r]);
                        sum[r] += p1;
                        st[(4 * g + r) * STG_LD + 16 + l15] = f2bf(p1);
                    } else {
                        st[(4 * g + r) * STG_LD + 16 + l15] = 0;   // padded keys
                    }
                }
            };

            // PV pipelined (r17): read prev chunk first, then stage next.
            f32x4 o0 = {0.f,0.f,0.f,0.f}, o1 = {0.f,0.f,0.f,0.f};
            stage_chunk(0, st0);                       // prologue: chunk 0 -> buf0
            #pragma unroll
            for (int kp = 0; kp < 7; ++kp) {
                u16* stc = st0 + (kp & 1) * (16 * STG_LD);
                short8_t aP  = *(const short8_t*)(stc + l15 * STG_LD + g * 8);
                short8_t bV0 = *(const short8_t*)(VTs + l15 * VT_LD + kp * 32 + g * 8);
                short8_t bV1 = *(const short8_t*)(VTs + (16 + l15) * VT_LD + kp * 32 + g * 8);
                if (kp < 6)
                    stage_chunk(kp + 1, st0 + ((kp + 1) & 1) * (16 * STG_LD));
                o0 = __builtin_amdgcn_mfma_f32_16x16x32_bf16(aP, bV0, o0, 0, 0, 0);
                o1 = __builtin_amdgcn_mfma_f32_16x16x32_bf16(aP, bV1, o1, 0, 0, 0);
            }
            #pragma unroll
            for (int r = 0; r < 4; ++r) {
                #pragma unroll
                for (int o = 1; o < 16; o <<= 1) sum[r] += __shfl_xor(sum[r], o, 64);
            }

            {
                u16* st = st0;
                #pragma unroll
                for (int r = 0; r < 4; ++r) {
                    float inv = 1.f / sum[r];
                    st[(4 * g + r) * STG_LD + l15]      = f2bf(o0[r] * inv);
                    st[(4 * g + r) * STG_LD + 16 + l15] = f2bf(o1[r] * inv);
                }
                short8_t aO = *(const short8_t*)(st + l15 * STG_LD + g * 8);
                #pragma unroll
                for (int nj = 0; nj < 6; ++nj) {
                    short8_t bw = *(const short8_t*)(pjT + (nj * 16 + l15) * 96 + h * 32 + g * 8);
                    po[im][nj] = __builtin_amdgcn_mfma_f32_16x16x32_bf16(aO, bw, po[im][nj], 0, 0, 0);
                }
            }
        }
        __syncthreads();     // last iteration: fences ABuf for the X2 alias
    }

    // =================================================================
    // Post-attn: register LN + bf16 X2 store (wave-private) + dual-tile
    // MLP. ZERO barriers. (r15/r16/r17-proven)
    // =================================================================
    float pb[6], g1v[6], b1v[6], g2v[6], b2v[6], fbv[6];
    #pragma unroll
    for (int nj = 0; nj < 6; ++nj) {
        int c = nj * 16 + l15;
        pb[nj]  = proj_b[c];
        g1v[nj] = g1[c];  b1v[nj] = b1[c];
        g2v[nj] = g2[c];  b2v[nj] = b2[c];
        fbv[nj] = fc2_b[c];
    }

    short8_t aYv[2][3];
    #pragma unroll
    for (int im = 0; im < 2; ++im) {
        int mt = w + NWV * im;
        int trow = mt * 16 + 4 * g;

        // ---- x2 = attn_out + proj_b (fp32 registers) ----
        f32x4 x2v[6];
        #pragma unroll
        for (int nj = 0; nj < 6; ++nj)
            #pragma unroll
            for (int r = 0; r < 4; ++r)
                x2v[nj][r] = po[im][nj][r] + pb[nj];

        // ---- LN1 stats per row 4g+r (nj-sum + 16-lane shfl) ----
        f32x4 s1 = {0.f,0.f,0.f,0.f}, s2 = {0.f,0.f,0.f,0.f};
        #pragma unroll
        for (int nj = 0; nj < 6; ++nj)
            #pragma unroll
            for (int r = 0; r < 4; ++r) {
                float v = x2v[nj][r];
                s1[r] += v; s2[r] += v * v;
            }
        #pragma unroll
        for (int r = 0; r < 4; ++r) {
            #pragma unroll
            for (int o = 1; o < 16; o <<= 1) {
                s1[r] += __shfl_xor(s1[r], o, 64);
                s2[r] += __shfl_xor(s2[r], o, 64);
            }
        }
        float mu[4], rs[4];
        #pragma unroll
        for (int r = 0; r < 4; ++r) {
            mu[r] = s1[r] * (1.f / 96.f);
            rs[r] = rsqrtf(s2[r] * (1.f / 96.f) - mu[r] * mu[r] + 1e-5f);
        }

        // ---- x2' = x2 + LN1(x2); LN2 stats alongside; bf16 store to X2 ----
        f32x4 t1 = {0.f,0.f,0.f,0.f}, t2 = {0.f,0.f,0.f,0.f};
        #pragma unroll
        for (int nj = 0; nj < 6; ++nj)
            #pragma unroll
            for (int r = 0; r < 4; ++r) {
                float v  = x2v[nj][r];
                float xp = v + (v - mu[r]) * rs[r] * g1v[nj] + b1v[nj];
                x2v[nj][r] = xp;
                t1[r] += xp; t2[r] += xp * xp;
                X2[(trow + r) * X2_LD + nj * 16 + l15] = f2bf(xp);   // wave-private row
            }
        #pragma unroll
        for (int r = 0; r < 4; ++r) {
            #pragma unroll
            for (int o = 1; o < 16; o <<= 1) {
                t1[r] += __shfl_xor(t1[r], o, 64);
                t2[r] += __shfl_xor(t2[r], o, 64);
            }
        }
        float mu2[4], rs2[4];
        #pragma unroll
        for (int r = 0; r < 4; ++r) {
            mu2[r] = t1[r] * (1.f / 96.f);
            rs2[r] = rsqrtf(t2[r] * (1.f / 96.f) - mu2[r] * mu2[r] + 1e-5f);
        }

        // ---- aY: LN2 affine at C-layout write, Stg transpose ----
        #pragma unroll
        for (int ks = 0; ks < 3; ++ks) {
            int njA = 2 * ks, njB = 2 * ks + 1;
            #pragma unroll
            for (int r = 0; r < 4; ++r) {
                st0[(4 * g + r) * STG_LD + l15] =
                    f2bf((x2v[njA][r] - mu2[r]) * rs2[r] * g2v[njA] + b2v[njA]);
                st0[(4 * g + r) * STG_LD + 16 + l15] =
                    f2bf((x2v[njB][r] - mu2[r]) * rs2[r] * g2v[njB] + b2v[njB]);
            }
            aYv[im][ks] = *(const short8_t*)(st0 + l15 * STG_LD + g * 8);   // in-order DS
        }
    }

    // ---- MLP hot loop: both M-tiles per k-step, shared weights ----
    f32x4 p2[2][6];
    #pragma unroll
    for (int im = 0; im < 2; ++im)
        #pragma unroll
        for (int nj = 0; nj < 6; ++nj) p2[im][nj] = (f32x4){0.f, 0.f, 0.f, 0.f};

    short8_t c1[2][3], n1[2][3];
    #pragma unroll
    for (int half = 0; half < 2; ++half)
        #pragma unroll
        for (int k2 = 0; k2 < 3; ++k2)
            c1[half][k2] = *(const short8_t*)(f1T + (half * 16 + l15) * 96 + k2 * 32 + g * 8);

    u16* const stA = st0;
    u16* const stB = st0 + 16 * STG_LD;

    for (int ks = 0; ks < 12; ++ks) {
        // fc2 weights for this ks (shared by both tiles)
        short8_t c2[6];
        #pragma unroll
        for (int nj = 0; nj < 6; ++nj)
            c2[nj] = *(const short8_t*)(f2T + (nj * 16 + l15) * 384 + ks * 32 + g * 8);

        // fc1 + gelu for both tiles into their stage buffers
        #pragma unroll
        for (int im = 0; im < 2; ++im) {
            u16* st = (im == 0) ? stA : stB;
            #pragma unroll
            for (int half = 0; half < 2; ++half) {
                int ncol = (ks * 2 + half) * 16 + l15;
                f32x4 acc = {0.f, 0.f, 0.f, 0.f};
                #pragma unroll
                for (int k2 = 0; k2 < 3; ++k2)
                    acc = __builtin_amdgcn_mfma_f32_16x16x32_bf16(aYv[im][k2], c1[half][k2], acc, 0, 0, 0);
                float bias = fc1_b[ncol];
                #pragma unroll
                for (int r = 0; r < 4; ++r)
                    st[(4 * g + r) * STG_LD + half * 16 + l15] = f2bf(gelu_f(acc[r] + bias));
            }
        }

        // prefetch next-iteration fc1 weights (latency hides under fc2)
        if (ks < 11) {
            #pragma unroll
            for (int half = 0; half < 2; ++half)
                #pragma unroll
                for (int k2 = 0; k2 < 3; ++k2)
                    n1[half][k2] = *(const short8_t*)(f1T + (((ks + 1) * 2 + half) * 16 + l15) * 96 + k2 * 32 + g * 8);
        }

        short8_t aH0 = *(const short8_t*)(stA + l15 * STG_LD + g * 8);
        short8_t aH1 = *(const short8_t*)(stB + l15 * STG_LD + g * 8);
        #pragma unroll
        for (int nj = 0; nj < 6; ++nj) {
            p2[0][nj] = __builtin_amdgcn_mfma_f32_16x16x32_bf16(aH0, c2[nj], p2[0][nj], 0, 0, 0);
            p2[1][nj] = __builtin_amdgcn_mfma_f32_16x16x32_bf16(aH1, c2[nj], p2[1][nj], 0, 0, 0);
        }

        #pragma unroll
        for (int half = 0; half < 2; ++half)
            #pragma unroll
            for (int k2 = 0; k2 < 3; ++k2)
                c1[half][k2] = n1[half][k2];
    }

    // ---- final: out = x2' + fc2_out + fc2_b, scatter via rowsL ----
    #pragma unroll
    for (int im = 0; im < 2; ++im) {
        int mt = w + NWV * im;
        int trow = mt * 16 + 4 * g;
        #pragma unroll
        for (int r = 0; r < 4; ++r) {
            int t = trow + r;
            if (t < NT) {
                float* orow = out + (size_t)rowsL[t] * C_;
                #pragma unroll
                for (int nj = 0; nj < 6; ++nj) {
                    int ncol = nj * 16 + l15;
                    orow[ncol] = bf2f(X2[t * X2_LD + ncol]) + p2[im][nj][r] + fbv[nj];
                }
            }
        }
    }
}

// =====================================================================
extern "C" void kernel_launch(void* const* d_in, const int* in_sizes, int n_in,
                              void* d_out, int out_size, void* d_ws, size_t ws_size,
                              hipStream_t stream)
{
    (void)in_sizes; (void)n_in; (void)out_size; (void)ws_size;

    const float* x      = (const float*)d_in[0];
    const float* qkv_w  = (const float*)d_in[1];
    const float* qkv_b  = (const float*)d_in[2];
    const float* proj_w = (const float*)d_in[3];
    const float* proj_b = (const float*)d_in[4];
    const float* g1     = (const float*)d_in[5];
    const float* b1     = (const float*)d_in[6];
    const float* g2     = (const float*)d_in[7];
    const float* b2     = (const float*)d_in[8];
    const float* fc1_w  = (const float*)d_in[9];
    const float* fc1_b  = (const float*)d_in[10];
    const float* fc2_w  = (const float*)d_in[11];
    const float* fc2_b  = (const float*)d_in[12];
    float* out = (float*)d_out;
    u16* ws = (u16*)d_ws;

    setup_kernel<<<128, 256, 0, stream>>>(qkv_w, proj_w, fc1_w, fc2_w, ws);
    fused_kernel<<<BW, 448, 0, stream>>>(x, ws, qkv_b, proj_b,
                                         g1, b1, g2, b2, fc1_b, fc2_b, out);
}

// Round 20
// 255.684 us; speedup vs baseline: 1.0826x; 1.0143x over previous
//
#include <hip/hip_runtime.h>
#include <hip/hip_bf16.h>

// ---- problem constants ----
#define B_     16
#define NBAND  4
#define HP     56
#define WP     56
#define C_     96
#define NHEADS 3
#define HD     32
#define NT     196                 // tokens per window
#define NTP    224                 // padded to 14x16
#define BW     1024                // windows
#define HID    384
#define NTOK   200704

typedef unsigned short u16;
typedef short s16;
typedef __attribute__((ext_vector_type(8))) s16   short8_t;  // 8 bf16 (4 VGPR)
typedef __attribute__((ext_vector_type(4))) s16   short4_t;
typedef __attribute__((ext_vector_type(4))) float f32x4;

__device__ __forceinline__ float bf2f(u16 u) {
    union { float f; unsigned int i; } x; x.i = ((unsigned int)u) << 16; return x.f;
}
// HW RNE conversion
__device__ __forceinline__ u16 f2bf(float f) {
    __hip_bfloat16 h = __float2bfloat16(f);
    union { __hip_bfloat16 h; u16 u; } c; c.h = h; return c.u;
}
// sigmoid-GELU: x * sigmoid(1.702x) (validated round 10)
__device__ __forceinline__ float gelu_f(float a) {
    return __fdividef(a, 1.0f + __expf(-1.702f * a));
}

// ---- workspace layout (bf16 elements) ----
#define WT_OFF   0          // qkv_w^T  [288][96]
#define PJT_OFF  27648      // proj_w^T [96][96]
#define F1T_OFF  36864      // fc1_w^T  [384][96]
#define F2T_OFF  73728      // fc2_w^T  [96][384]
#define WS_ELEMS 110592     // * 2 bytes = 221,184 B

__global__ __launch_bounds__(256) void setup_kernel(
    const float* __restrict__ qkv_w, const float* __restrict__ proj_w,
    const float* __restrict__ fc1_w, const float* __restrict__ fc2_w,
    u16* __restrict__ ws)
{
    int i0 = blockIdx.x * 256 + threadIdx.x;
    int stride = gridDim.x * 256;
    for (int e = i0; e < 27648; e += stride) {          // wT[n][k] = qkv_w[k][n]
        int n = e / 96, k = e - n * 96;
        ws[WT_OFF + e] = f2bf(qkv_w[k * 288 + n]);
    }
    for (int e = i0; e < 9216; e += stride) {           // pjT[n][k]
        int n = e / 96, k = e - n * 96;
        ws[PJT_OFF + e] = f2bf(proj_w[k * 96 + n]);
    }
    for (int e = i0; e < 36864; e += stride) {          // f1T[n][k], n<384
        int n = e / 96, k = e - n * 96;
        ws[F1T_OFF + e] = f2bf(fc1_w[k * 384 + n]);
    }
    for (int e = i0; e < 36864; e += stride) {          // f2T[n][k], n<96, k<384
        int n = e / 384, k = e - n * 384;
        ws[F2T_OFF + e] = f2bf(fc2_w[k * 96 + n]);
    }
}

// =====================================================================
// FUSED kernel v9 = r19 (best, 259.3us) + T5 s_setprio(1) around MFMA
// clusters (QK^T batch, PV pairs, proj, QKV, MLP). Zero numerical
// effect — absmax must stay exactly 0.0390625.
// =====================================================================
#define NWV    7
#define QK_LD  40    // Q/K row stride (u16)
#define VT_LD  232   // V^T row stride
#define STG_LD 40    // per-wave staging row stride
#define X2_LD  104   // x2' row stride (u16)
#define ABUF_ELEMS (2 * NTP * QK_LD + HD * VT_LD)   // 25,344 u16 = 50,688 B

__global__ __launch_bounds__(448) void fused_kernel(
    const float* __restrict__ x,
    const u16*  __restrict__ ws,
    const float* __restrict__ qkv_b,
    const float* __restrict__ proj_b,
    const float* __restrict__ g1, const float* __restrict__ b1,
    const float* __restrict__ g2, const float* __restrict__ b2,
    const float* __restrict__ fc1_b, const float* __restrict__ fc2_b,
    float* __restrict__ out)
{
    __shared__ __align__(16) u16 ABuf[ABUF_ELEMS];           // Qs|Ks|VTs, later X2 (bf16)
    __shared__ __align__(16) u16 Stg[NWV * 2 * 16 * STG_LD]; // 17,920 B
    __shared__ int rowsL[NT];                                //    784 B

    u16* const Qs  = ABuf;
    u16* const Ks  = ABuf + NTP * QK_LD;
    u16* const VTs = ABuf + 2 * NTP * QK_LD;
    u16* const X2  = ABuf;       // alias after head loop; 224*104*2 = 46,592 B

    const int wi  = blockIdx.x;
    const int b   = wi >> 6, ih = (wi >> 3) & 7, iw = wi & 7;
    const int tid = threadIdx.x;
    const int w   = tid >> 6, lane = tid & 63;
    const int l15 = lane & 15, g = lane >> 4;

    // token t=(n,r,col) -> flat row; roll(-3) gather == roll(+3) scatter
    if (tid < NT) {
        int t = tid;
        int n = t / 49, rc = t - n * 49, r = rc / 7, cl = rc - r * 7;
        int hh = ih * 7 + r  + 3; if (hh >= HP) hh -= HP;
        int ww = iw * 7 + cl + 3; if (ww >= WP) ww -= WP;
        rowsL[t] = ((b * NBAND + n) * HP + hh) * WP + ww;
    }
    __syncthreads();

    const u16* wT  = ws + WT_OFF;
    const u16* pjT = ws + PJT_OFF;
    const u16* f1T = ws + F1T_OFF;
    const u16* f2T = ws + F2T_OFF;

    // ---- preload x A-fragments for both owned M-tiles (head-invariant) ----
    short8_t ax[2][3];
    #pragma unroll
    for (int im = 0; im < 2; ++im) {
        int mt = w + NWV * im;
        int t  = mt * 16 + l15;
        bool valid = (t < NT);
        const float* xb = x + (valid ? (size_t)rowsL[t] * C_ : 0);
        #pragma unroll
        for (int ks = 0; ks < 3; ++ks) {
            short8_t a;
            if (valid) {
                const float* p = xb + ks * 32 + g * 8;
                #pragma unroll
                for (int j = 0; j < 8; ++j) a[j] = (s16)f2bf(p[j]);
            } else {
                #pragma unroll
                for (int j = 0; j < 8; ++j) a[j] = 0;
            }
            ax[im][ks] = a;
        }
    }

    f32x4 po[2][6];                       // proj accumulators
    #pragma unroll
    for (int im = 0; im < 2; ++im)
        #pragma unroll
        for (int nj = 0; nj < 6; ++nj)
            po[im][nj] = (f32x4){0.f, 0.f, 0.f, 0.f};

    u16* const st0 = Stg + w * (2 * 16 * STG_LD);

    for (int h = 0; h < NHEADS; ++h) {
        // ---- QKV GEMM for head h: nj outer, B-frags/bias shared (r16) ----
        #pragma unroll
        for (int nj = 0; nj < 6; ++nj) {
            int mat = nj >> 1, nh = nj & 1;
            int ncol = mat * 96 + h * 32 + nh * 16 + l15;
            short8_t bw[3];
            #pragma unroll
            for (int ks = 0; ks < 3; ++ks)
                bw[ks] = *(const short8_t*)(wT + ncol * 96 + ks * 32 + g * 8);
            float bias = qkv_b[ncol];
            int d = nh * 16 + l15;
            #pragma unroll
            for (int im = 0; im < 2; ++im) {
                int mt = w + NWV * im;
                f32x4 acc = {0.f, 0.f, 0.f, 0.f};
                __builtin_amdgcn_s_setprio(1);
                #pragma unroll
                for (int ks = 0; ks < 3; ++ks)
                    acc = __builtin_amdgcn_mfma_f32_16x16x32_bf16(ax[im][ks], bw[ks], acc, 0, 0, 0);
                __builtin_amdgcn_s_setprio(0);
                int trow = mt * 16 + 4 * g;
                if (mat == 0) {
                    // hd^-0.5 * log2(e) folded into Q -> softmax via raw v_exp
                    const float sc = 0.25503492f;
                    #pragma unroll
                    for (int r = 0; r < 4; ++r)
                        Qs[(trow + r) * QK_LD + d] = f2bf((acc[r] + bias) * sc);
                } else if (mat == 1) {
                    #pragma unroll
                    for (int r = 0; r < 4; ++r)
                        Ks[(trow + r) * QK_LD + d] = f2bf(acc[r] + bias);
                } else {                       // V stored transposed
                    short4_t v4;
                    #pragma unroll
                    for (int r = 0; r < 4; ++r) v4[r] = (s16)f2bf(acc[r] + bias);
                    *(short4_t*)(VTs + d * VT_LD + trow) = v4;
                }
            }
        }
        __syncthreads();

        // ---- attention + per-head proj accumulate ----
        #pragma unroll
        for (int im = 0; im < 2; ++im) {
            int mt = w + NWV * im;
            short8_t aQ = *(const short8_t*)(Qs + (mt * 16 + l15) * QK_LD + g * 8);
            f32x4 s[13];
            __builtin_amdgcn_s_setprio(1);
            #pragma unroll
            for (int kt = 0; kt < 13; ++kt) {
                short8_t bK = *(const short8_t*)(Ks + (kt * 16 + l15) * QK_LD + g * 8);
                f32x4 z = {0.f, 0.f, 0.f, 0.f};
                s[kt] = __builtin_amdgcn_mfma_f32_16x16x32_bf16(aQ, bK, z, 0, 0, 0);
            }
            __builtin_amdgcn_s_setprio(0);
            if (l15 >= 4) {                   // keys 192+l15 >= 196 invalid
                #pragma unroll
                for (int r = 0; r < 4; ++r) s[12][r] = -1e30f;
            }
            float m[4], sum[4];
            #pragma unroll
            for (int r = 0; r < 4; ++r) {
                // pairwise max tree (depth 4)
                float a0 = fmaxf(s[0][r],  s[1][r]);
                float a1 = fmaxf(s[2][r],  s[3][r]);
                float a2 = fmaxf(s[4][r],  s[5][r]);
                float a3 = fmaxf(s[6][r],  s[7][r]);
                float a4 = fmaxf(s[8][r],  s[9][r]);
                float a5 = fmaxf(s[10][r], s[11][r]);
                float b0 = fmaxf(a0, a1);
                float b1 = fmaxf(a2, a3);
                float b2 = fmaxf(a4, a5);
                float c0 = fmaxf(b0, b1);
                float c1 = fmaxf(b2, s[12][r]);
                float mm = fmaxf(c0, c1);
                #pragma unroll
                for (int o = 1; o < 16; o <<= 1) mm = fmaxf(mm, __shfl_xor(mm, o, 64));
                m[r] = mm;
                sum[r] = 0.f;
            }

            // raw v_exp_f32 per element; sum order 0..6 (logits pre-scaled)
            auto stage_chunk = [&](int kp, u16* st) {
                #pragma unroll
                for (int r = 0; r < 4; ++r) {
                    float p0 = __builtin_amdgcn_exp2f(s[2 * kp][r] - m[r]);
                    sum[r] += p0;
                    st[(4 * g + r) * STG_LD + l15] = f2bf(p0);
                    if (kp < 6) {
                        float p1 = __builtin_amdgcn_exp2f(s[2 * kp + 1][r] - m[r]);
                        sum[r] += p1;
                        st[(4 * g + r) * STG_LD + 16 + l15] = f2bf(p1);
                    } else {
                        st[(4 * g + r) * STG_LD + 16 + l15] = 0;   // padded keys
                    }
                }
            };

            // PV pipelined (r17): read prev chunk first, then stage next.
            f32x4 o0 = {0.f,0.f,0.f,0.f}, o1 = {0.f,0.f,0.f,0.f};
            stage_chunk(0, st0);                       // prologue: chunk 0 -> buf0
            #pragma unroll
            for (int kp = 0; kp < 7; ++kp) {
                u16* stc = st0 + (kp & 1) * (16 * STG_LD);
                short8_t aP  = *(const short8_t*)(stc + l15 * STG_LD + g * 8);
                short8_t bV0 = *(const short8_t*)(VTs + l15 * VT_LD + kp * 32 + g * 8);
                short8_t bV1 = *(const short8_t*)(VTs + (16 + l15) * VT_LD + kp * 32 + g * 8);
                if (kp < 6)
                    stage_chunk(kp + 1, st0 + ((kp + 1) & 1) * (16 * STG_LD));
                __builtin_amdgcn_s_setprio(1);
                o0 = __builtin_amdgcn_mfma_f32_16x16x32_bf16(aP, bV0, o0, 0, 0, 0);
                o1 = __builtin_amdgcn_mfma_f32_16x16x32_bf16(aP, bV1, o1, 0, 0, 0);
                __builtin_amdgcn_s_setprio(0);
            }
            #pragma unroll
            for (int r = 0; r < 4; ++r) {
                #pragma unroll
                for (int o = 1; o < 16; o <<= 1) sum[r] += __shfl_xor(sum[r], o, 64);
            }

            {
                u16* st = st0;
                #pragma unroll
                for (int r = 0; r < 4; ++r) {
                    float inv = 1.f / sum[r];
                    st[(4 * g + r) * STG_LD + l15]      = f2bf(o0[r] * inv);
                    st[(4 * g + r) * STG_LD + 16 + l15] = f2bf(o1[r] * inv);
                }
                short8_t aO = *(const short8_t*)(st + l15 * STG_LD + g * 8);
                __builtin_amdgcn_s_setprio(1);
                #pragma unroll
                for (int nj = 0; nj < 6; ++nj) {
                    short8_t bw = *(const short8_t*)(pjT + (nj * 16 + l15) * 96 + h * 32 + g * 8);
                    po[im][nj] = __builtin_amdgcn_mfma_f32_16x16x32_bf16(aO, bw, po[im][nj], 0, 0, 0);
                }
                __builtin_amdgcn_s_setprio(0);
            }
        }
        __syncthreads();     // last iteration: fences ABuf for the X2 alias
    }

    // =================================================================
    // Post-attn: register LN + bf16 X2 store (wave-private) + dual-tile
    // MLP. ZERO barriers. (r15/r16/r17-proven)
    // =================================================================
    float pb[6], g1v[6], b1v[6], g2v[6], b2v[6], fbv[6];
    #pragma unroll
    for (int nj = 0; nj < 6; ++nj) {
        int c = nj * 16 + l15;
        pb[nj]  = proj_b[c];
        g1v[nj] = g1[c];  b1v[nj] = b1[c];
        g2v[nj] = g2[c];  b2v[nj] = b2[c];
        fbv[nj] = fc2_b[c];
    }

    short8_t aYv[2][3];
    #pragma unroll
    for (int im = 0; im < 2; ++im) {
        int mt = w + NWV * im;
        int trow = mt * 16 + 4 * g;

        // ---- x2 = attn_out + proj_b (fp32 registers) ----
        f32x4 x2v[6];
        #pragma unroll
        for (int nj = 0; nj < 6; ++nj)
            #pragma unroll
            for (int r = 0; r < 4; ++r)
                x2v[nj][r] = po[im][nj][r] + pb[nj];

        // ---- LN1 stats per row 4g+r (nj-sum + 16-lane shfl) ----
        f32x4 s1 = {0.f,0.f,0.f,0.f}, s2 = {0.f,0.f,0.f,0.f};
        #pragma unroll
        for (int nj = 0; nj < 6; ++nj)
            #pragma unroll
            for (int r = 0; r < 4; ++r) {
                float v = x2v[nj][r];
                s1[r] += v; s2[r] += v * v;
            }
        #pragma unroll
        for (int r = 0; r < 4; ++r) {
            #pragma unroll
            for (int o = 1; o < 16; o <<= 1) {
                s1[r] += __shfl_xor(s1[r], o, 64);
                s2[r] += __shfl_xor(s2[r], o, 64);
            }
        }
        float mu[4], rs[4];
        #pragma unroll
        for (int r = 0; r < 4; ++r) {
            mu[r] = s1[r] * (1.f / 96.f);
            rs[r] = rsqrtf(s2[r] * (1.f / 96.f) - mu[r] * mu[r] + 1e-5f);
        }

        // ---- x2' = x2 + LN1(x2); LN2 stats alongside; bf16 store to X2 ----
        f32x4 t1 = {0.f,0.f,0.f,0.f}, t2 = {0.f,0.f,0.f,0.f};
        #pragma unroll
        for (int nj = 0; nj < 6; ++nj)
            #pragma unroll
            for (int r = 0; r < 4; ++r) {
                float v  = x2v[nj][r];
                float xp = v + (v - mu[r]) * rs[r] * g1v[nj] + b1v[nj];
                x2v[nj][r] = xp;
                t1[r] += xp; t2[r] += xp * xp;
                X2[(trow + r) * X2_LD + nj * 16 + l15] = f2bf(xp);   // wave-private row
            }
        #pragma unroll
        for (int r = 0; r < 4; ++r) {
            #pragma unroll
            for (int o = 1; o < 16; o <<= 1) {
                t1[r] += __shfl_xor(t1[r], o, 64);
                t2[r] += __shfl_xor(t2[r], o, 64);
            }
        }
        float mu2[4], rs2[4];
        #pragma unroll
        for (int r = 0; r < 4; ++r) {
            mu2[r] = t1[r] * (1.f / 96.f);
            rs2[r] = rsqrtf(t2[r] * (1.f / 96.f) - mu2[r] * mu2[r] + 1e-5f);
        }

        // ---- aY: LN2 affine at C-layout write, Stg transpose ----
        #pragma unroll
        for (int ks = 0; ks < 3; ++ks) {
            int njA = 2 * ks, njB = 2 * ks + 1;
            #pragma unroll
            for (int r = 0; r < 4; ++r) {
                st0[(4 * g + r) * STG_LD + l15] =
                    f2bf((x2v[njA][r] - mu2[r]) * rs2[r] * g2v[njA] + b2v[njA]);
                st0[(4 * g + r) * STG_LD + 16 + l15] =
                    f2bf((x2v[njB][r] - mu2[r]) * rs2[r] * g2v[njB] + b2v[njB]);
            }
            aYv[im][ks] = *(const short8_t*)(st0 + l15 * STG_LD + g * 8);   // in-order DS
        }
    }

    // ---- MLP hot loop: both M-tiles per k-step, shared weights ----
    f32x4 p2[2][6];
    #pragma unroll
    for (int im = 0; im < 2; ++im)
        #pragma unroll
        for (int nj = 0; nj < 6; ++nj) p2[im][nj] = (f32x4){0.f, 0.f, 0.f, 0.f};

    short8_t c1[2][3], n1[2][3];
    #pragma unroll
    for (int half = 0; half < 2; ++half)
        #pragma unroll
        for (int k2 = 0; k2 < 3; ++k2)
            c1[half][k2] = *(const short8_t*)(f1T + (half * 16 + l15) * 96 + k2 * 32 + g * 8);

    u16* const stA = st0;
    u16* const stB = st0 + 16 * STG_LD;

    for (int ks = 0; ks < 12; ++ks) {
        // fc2 weights for this ks (shared by both tiles)
        short8_t c2[6];
        #pragma unroll
        for (int nj = 0; nj < 6; ++nj)
            c2[nj] = *(const short8_t*)(f2T + (nj * 16 + l15) * 384 + ks * 32 + g * 8);

        // fc1 + gelu for both tiles into their stage buffers
        #pragma unroll
        for (int im = 0; im < 2; ++im) {
            u16* st = (im == 0) ? stA : stB;
            #pragma unroll
            for (int half = 0; half < 2; ++half) {
                int ncol = (ks * 2 + half) * 16 + l15;
                f32x4 acc = {0.f, 0.f, 0.f, 0.f};
                __builtin_amdgcn_s_setprio(1);
                #pragma unroll
                for (int k2 = 0; k2 < 3; ++k2)
                    acc = __builtin_amdgcn_mfma_f32_16x16x32_bf16(aYv[im][k2], c1[half][k2], acc, 0, 0, 0);
                __builtin_amdgcn_s_setprio(0);
                float bias = fc1_b[ncol];
                #pragma unroll
                for (int r = 0; r < 4; ++r)
                    st[(4 * g + r) * STG_LD + half * 16 + l15] = f2bf(gelu_f(acc[r] + bias));
            }
        }

        // prefetch next-iteration fc1 weights (latency hides under fc2)
        if (ks < 11) {
            #pragma unroll
            for (int half = 0; half < 2; ++half)
                #pragma unroll
                for (int k2 = 0; k2 < 3; ++k2)
                    n1[half][k2] = *(const short8_t*)(f1T + (((ks + 1) * 2 + half) * 16 + l15) * 96 + k2 * 32 + g * 8);
        }

        short8_t aH0 = *(const short8_t*)(stA + l15 * STG_LD + g * 8);
        short8_t aH1 = *(const short8_t*)(stB + l15 * STG_LD + g * 8);
        __builtin_amdgcn_s_setprio(1);
        #pragma unroll
        for (int nj = 0; nj < 6; ++nj) {
            p2[0][nj] = __builtin_amdgcn_mfma_f32_16x16x32_bf16(aH0, c2[nj], p2[0][nj], 0, 0, 0);
            p2[1][nj] = __builtin_amdgcn_mfma_f32_16x16x32_bf16(aH1, c2[nj], p2[1][nj], 0, 0, 0);
        }
        __builtin_amdgcn_s_setprio(0);

        #pragma unroll
        for (int half = 0; half < 2; ++half)
            #pragma unroll
            for (int k2 = 0; k2 < 3; ++k2)
                c1[half][k2] = n1[half][k2];
    }

    // ---- final: out = x2' + fc2_out + fc2_b, scatter via rowsL ----
    #pragma unroll
    for (int im = 0; im < 2; ++im) {
        int mt = w + NWV * im;
        int trow = mt * 16 + 4 * g;
        #pragma unroll
        for (int r = 0; r < 4; ++r) {
            int t = trow + r;
            if (t < NT) {
                float* orow = out + (size_t)rowsL[t] * C_;
                #pragma unroll
                for (int nj = 0; nj < 6; ++nj) {
                    int ncol = nj * 16 + l15;
                    orow[ncol] = bf2f(X2[t * X2_LD + ncol]) + p2[im][nj][r] + fbv[nj];
                }
            }
        }
    }
}

// =====================================================================
extern "C" void kernel_launch(void* const* d_in, const int* in_sizes, int n_in,
                              void* d_out, int out_size, void* d_ws, size_t ws_size,
                              hipStream_t stream)
{
    (void)in_sizes; (void)n_in; (void)out_size; (void)ws_size;

    const float* x      = (const float*)d_in[0];
    const float* qkv_w  = (const float*)d_in[1];
    const float* qkv_b  = (const float*)d_in[2];
    const float* proj_w = (const float*)d_in[3];
    const float* proj_b = (const float*)d_in[4];
    const float* g1     = (const float*)d_in[5];
    const float* b1     = (const float*)d_in[6];
    const float* g2     = (const float*)d_in[7];
    const float* b2     = (const float*)d_in[8];
    const float* fc1_w  = (const float*)d_in[9];
    const float* fc1_b  = (const float*)d_in[10];
    const float* fc2_w  = (const float*)d_in[11];
    const float* fc2_b  = (const float*)d_in[12];
    float* out = (float*)d_out;
    u16* ws = (u16*)d_ws;

    setup_kernel<<<128, 256, 0, stream>>>(qkv_w, proj_w, fc1_w, fc2_w, ws);
    fused_kernel<<<BW, 448, 0, stream>>>(x, ws, qkv_b, proj_b,
                                         g1, b1, g2, b2, fc1_b, fc2_b, out);
}